// Round 11
// baseline (960.346 us; speedup 1.0000x reference)
//
#include <hip/hip_runtime.h>
#include <hip/hip_fp16.h>

typedef _Float16 f16;
typedef _Float16 f16x8 __attribute__((ext_vector_type(8)));
typedef _Float16 f16x4 __attribute__((ext_vector_type(4)));
typedef float f32x4 __attribute__((ext_vector_type(4)));

#define B_ 1024
#define T_ 128
#define F_ 9
#define H_ 256
#define P_ 2048

typedef unsigned long long ull;
#define AL(p) __hip_atomic_load((p), __ATOMIC_RELAXED, __HIP_MEMORY_SCOPE_AGENT)
#define AS(p, v) __hip_atomic_store((p), (v), __ATOMIC_RELAXED, __HIP_MEMORY_SCOPE_AGENT)

// ---------------- helpers ----------------
__device__ __forceinline__ float sigf(float x) { return 1.f / (1.f + __expf(-x)); }
__device__ __forceinline__ float tanh_(float x) {
  float a = fminf(fabsf(x), 12.f);
  float e = __expf(2.f * a);
  float r = 1.f - 2.f / (e + 1.f);
  return copysignf(r, x);
}

__device__ __forceinline__ f16x8 aload16(const f16* p) {
  union { ull u[2]; f16x8 v; } r;
  r.u[0] = AL((const ull*)p);
  r.u[1] = AL((const ull*)p + 1);
  return r.v;
}

__device__ __forceinline__ float blk_sum(float v) {
  __shared__ float sh[8];
  int lane = threadIdx.x & 63, w = threadIdx.x >> 6;
  int nw = blockDim.x >> 6;
#pragma unroll
  for (int o = 32; o > 0; o >>= 1) v += __shfl_xor(v, o, 64);
  __syncthreads();
  if (lane == 0) sh[w] = v;
  __syncthreads();
  float t = 0.f;
  for (int i = 0; i < nw; i++) t += sh[i];
  return t;
}

// ---------------- 64x64-tile fp16 MFMA GEMM (tail shapes) -----------------
__global__ __launch_bounds__(256) void gemm64(
    const f16* __restrict__ A, int lda,
    const f16* __restrict__ Bt, int ldb,
    const float* __restrict__ bias,
    f16* __restrict__ o16, int ldo16,
    float* __restrict__ o32, int ldo32,
    f16* __restrict__ o16t, int ldt,
    int M, int N, int K)
{
  __shared__ __align__(16) f16 As[64][40];
  __shared__ __align__(16) f16 Bs[64][40];
  const int tid = threadIdx.x;
  const int lane = tid & 63, wave = tid >> 6;
  const int q = lane >> 4, l15 = lane & 15;
  const int bm = blockIdx.x * 64, bn = blockIdx.y * 64;

  f32x4 acc[4];
#pragma unroll
  for (int tn = 0; tn < 4; tn++) acc[tn] = (f32x4){0.f, 0.f, 0.f, 0.f};

  for (int k0 = 0; k0 < K; k0 += 32) {
    int row = tid >> 2, kh = (tid & 3) * 8;
    *(f16x8*)&As[row][kh] = *(const f16x8*)&A[(size_t)(bm + row) * lda + k0 + kh];
    *(f16x8*)&Bs[row][kh] = *(const f16x8*)&Bt[(size_t)(bn + row) * ldb + k0 + kh];
    __syncthreads();
    f16x8 af = *(const f16x8*)&As[wave * 16 + l15][q * 8];
#pragma unroll
    for (int tn = 0; tn < 4; tn++) {
      f16x8 bf = *(const f16x8*)&Bs[tn * 16 + l15][q * 8];
      acc[tn] = __builtin_amdgcn_mfma_f32_16x16x32_f16(af, bf, acc[tn], 0, 0, 0);
    }
    __syncthreads();
  }
#pragma unroll
  for (int tn = 0; tn < 4; tn++) {
    int colg = bn + tn * 16 + l15;
    float bv = bias ? bias[colg] : 0.f;
#pragma unroll
    for (int r = 0; r < 4; r++) {
      int rowg = bm + wave * 16 + q * 4 + r;
      float v = acc[tn][r] + bv;
      if (o32) o32[(size_t)rowg * ldo32 + colg] = v;
      if (o16) o16[(size_t)rowg * ldo16 + colg] = (f16)v;
      if (o16t) o16t[(size_t)colg * ldt + rowg] = (f16)v;
    }
  }
}

// ---------------- LSTM v7 (R6, proven 726us): pipeline + flags + own-LDS --
// Both layers pipelined, in place on hio, v2 counter-protocol semantics.
// Six protocol variants bracket this structure's floor at 726-832us; the
// 1-block/CU 2-layer pipeline is register-optimal (256 KB weights/slice).
__global__ __launch_bounds__(256, 1) void lstm_pipe(
    f16* __restrict__ hio,
    const f16* __restrict__ wpk0, const f16* __restrict__ wpk1,
    const float* __restrict__ b0, const float* __restrict__ b1,
    int* __restrict__ cnt0, int* __restrict__ cnt1)
{
  __shared__ __align__(16) f16 apf[2][16][64][8];   // A-frags per M-tile, 32 KB
  __shared__ __align__(16) f16 htile[32][64];       // 4 KB
  const int tid = threadIdx.x;
  const int lane = tid & 63, w = tid >> 6;          // wave 0..3
  const int q = lane >> 4, l15 = lane & 15;
  const int layer = blockIdx.x >> 7;                // 0..127 -> L0, 128..255 -> L1
  const int lbid = blockIdx.x & 127;
  const int grp = lbid & 31, s = lbid >> 5;         // 32 groups x 4 col-slices
  const int m0 = grp * 32;
  const f16* wpk = layer ? wpk1 : wpk0;
  const float* bias = layer ? b1 : b0;
  int* myflags = (layer ? cnt1 : cnt0) + grp * 64;  // slots [0..3], 256B apart
  int* xflags  = cnt0 + grp * 64;                   // layer 1 watches layer 0

  const int own0 = ((w >> 1) == s);                 // k = 8+w is own-col
  const int own1 = (((w + 4) >> 1) == s);           // k = 12+w is own-col
  const int offh = (w & 1) * 32;                    // htile col offset for own k

  // ---- weight slice into registers: 64 x f16x8 = 256 regs/lane ----
  f16x8 bf[4][16];
  {
    const f16* wbase = wpk + (((size_t)(s * 4 + w) * 4) * 16) * 512 + lane * 8;
#pragma unroll
    for (int g = 0; g < 4; g++)
#pragma unroll
      for (int k = 0; k < 16; k++)
        bf[g][k] = *(const f16x8*)(wbase + (size_t)(g * 16 + k) * 512);
  }
  float bv[4];
#pragma unroll
  for (int g = 0; g < 4; g++) bv[g] = bias[g * 256 + s * 64 + w * 16 + l15];

  const int srow = lane & 15, scb = lane >> 4;
  size_t rb[2];
  rb[0] = ((size_t)(m0 + srow) * T_) * 256 + scb * 8;
  rb[1] = ((size_t)(m0 + 16 + srow) * T_) * 256 + scb * 8;

  const f16x8 zv = {(f16)0, (f16)0, (f16)0, (f16)0, (f16)0, (f16)0, (f16)0, (f16)0};

  // pre-loop: layer 1 waits for h0_0 (L0 flags >= 2) before reading x_0
  if (layer) {
    if (tid == 0) {
      int it = 0;
      for (;;) {
        ull a = AL((ull*)xflags);
        ull b2 = AL((ull*)xflags + 1);
        if ((int)a >= 2 && (int)(a >> 32) >= 2 &&
            (int)b2 >= 2 && (int)(b2 >> 32) >= 2) break;
        __builtin_amdgcn_s_sleep(1);
        if (++it > (1 << 22)) break;
      }
    }
    __syncthreads();
  }
  f16x8 xr[2][2];
#pragma unroll
  for (int mt = 0; mt < 2; mt++) {
    if (layer) {
      xr[mt][0] = aload16(&hio[rb[mt] + (size_t)w * 32]);
      xr[mt][1] = aload16(&hio[rb[mt] + (size_t)(w + 4) * 32]);
    } else {
      xr[mt][0] = *(const f16x8*)&hio[rb[mt] + (size_t)w * 32];
      xr[mt][1] = *(const f16x8*)&hio[rb[mt] + (size_t)(w + 4) * 32];
    }
  }
  float cst[2][4] = {{0.f, 0.f, 0.f, 0.f}, {0.f, 0.f, 0.f, 0.f}};

  __syncthreads();                   // drains all lanes' x_0 loads
  if (tid == 0) AS(&myflags[s], 1);  // initial signal: x_0 prefetched

  for (int t = 0; t < T_; ++t) {
    // ---- phase A: own group done step t-1; (L1) L0 done step t+1 ----
    if (tid == 0) {
      const int needO = t + 1;
      int needX = 0;
      if (layer) { needX = t + 3; if (needX > T_ + 1) needX = T_ + 1; }
      int it = 0;
      for (;;) {
        ull a = AL((ull*)myflags);
        ull b2 = AL((ull*)myflags + 1);
        bool ok = (int)a >= needO && (int)(a >> 32) >= needO &&
                  (int)b2 >= needO && (int)(b2 >> 32) >= needO;
        if (ok && layer) {
          ull c = AL((ull*)xflags);
          ull d = AL((ull*)xflags + 1);
          ok = (int)c >= needX && (int)(c >> 32) >= needX &&
               (int)d >= needX && (int)(d >> 32) >= needX;
        }
        if (ok) break;
        __builtin_amdgcn_s_sleep(1);
        if (++it > (1 << 22)) break;   // bailout: wrong answer beats a hang
      }
    }
    __syncthreads();                 // S0

    // ---- stage x_t (prefetch regs) + h_{t-1} (own: LDS, remote: MALL) ----
#pragma unroll
    for (int mt = 0; mt < 2; mt++) {
      *(f16x8*)&apf[mt][w][lane][0]     = xr[mt][0];
      *(f16x8*)&apf[mt][w + 4][lane][0] = xr[mt][1];
      f16x8 h0 = zv, h1 = zv;
      if (t > 0) {
        if (own0) h0 = *(const f16x8*)&htile[mt * 16 + srow][offh + scb * 8];
        else      h0 = aload16(&hio[rb[mt] + (size_t)(t - 1) * 256 + (size_t)w * 32]);
        if (own1) h1 = *(const f16x8*)&htile[mt * 16 + srow][offh + scb * 8];
        else      h1 = aload16(&hio[rb[mt] + (size_t)(t - 1) * 256 + (size_t)(w + 4) * 32]);
      }
      *(f16x8*)&apf[mt][8 + w][lane][0]  = h0;
      *(f16x8*)&apf[mt][12 + w][lane][0] = h1;
    }
    __syncthreads();                 // S1: apf staged (htile reads done too)

    // ---- compute: 128 MFMAs (2 M-tiles), B-operands in registers ----
    f32x4 acc[2][4];
#pragma unroll
    for (int mt = 0; mt < 2; mt++)
#pragma unroll
      for (int g = 0; g < 4; g++) acc[mt][g] = (f32x4){0.f, 0.f, 0.f, 0.f};
#pragma unroll
    for (int k = 0; k < 16; k++) {
      f16x8 a0 = *(const f16x8*)&apf[0][k][lane][0];
      f16x8 a1 = *(const f16x8*)&apf[1][k][lane][0];
#pragma unroll
      for (int g = 0; g < 4; g++) {
        acc[0][g] = __builtin_amdgcn_mfma_f32_16x16x32_f16(a0, bf[g][k], acc[0][g], 0, 0, 0);
        acc[1][g] = __builtin_amdgcn_mfma_f32_16x16x32_f16(a1, bf[g][k], acc[1][g], 0, 0, 0);
      }
    }
    // prefetch x_{t+1}; for L1 this is h0_{t+1}, guaranteed by phase-A xflags
    if (t + 1 < T_) {
#pragma unroll
      for (int mt = 0; mt < 2; mt++) {
        if (layer) {
          xr[mt][0] = aload16(&hio[rb[mt] + (size_t)(t + 1) * 256 + (size_t)w * 32]);
          xr[mt][1] = aload16(&hio[rb[mt] + (size_t)(t + 1) * 256 + (size_t)(w + 4) * 32]);
        } else {
          xr[mt][0] = *(const f16x8*)&hio[rb[mt] + (size_t)(t + 1) * 256 + (size_t)w * 32];
          xr[mt][1] = *(const f16x8*)&hio[rb[mt] + (size_t)(t + 1) * 256 + (size_t)(w + 4) * 32];
        }
      }
    }
    // gate math (lane: rows mt*16 + q*4+r, col s*64+w*16+l15)
    f16 hn[2][4];
#pragma unroll
    for (int mt = 0; mt < 2; mt++)
#pragma unroll
      for (int r = 0; r < 4; r++) {
        float ip = acc[mt][0][r] + bv[0];
        float fp = acc[mt][1][r] + bv[1];
        float gp = acc[mt][2][r] + bv[2];
        float op = acc[mt][3][r] + bv[3];
        float cn = sigf(fp) * cst[mt][r] + sigf(ip) * tanh_(gp);
        cst[mt][r] = cn;
        hn[mt][r] = (f16)(sigf(op) * tanh_(cn));
      }
    // htile rewrite safe: stage-readers behind S1; store-readers behind S0/S1.
#pragma unroll
    for (int mt = 0; mt < 2; mt++)
#pragma unroll
      for (int r = 0; r < 4; r++)
        htile[mt * 16 + q * 4 + r][w * 16 + l15] = hn[mt][r];
    __syncthreads();                 // S3: htile ready
    {                                // write h_t over slot t (16B/thread)
      int row = tid >> 3, c8 = (tid & 7) * 8;
      union { ull u[2]; f16x8 v; } uh;
      uh.v = *(const f16x8*)&htile[row][c8];
      ull* dst =
          (ull*)&hio[((size_t)(m0 + row) * T_ + t) * 256 + s * 64 + c8];
      AS(dst, uh.u[0]);
      AS(dst + 1, uh.u[1]);
    }
    __syncthreads();                 // S4: drains h stores + xr prefetch loads
    if (tid == 0) AS(&myflags[s], t + 2);
  }
}

// ---------------- fused attention: q + qk + pool + vproj in one kernel ----
__global__ __launch_bounds__(256) void attn_fused_kernel(
    const f16* __restrict__ hseq, const f16* __restrict__ attninf,
    const float* __restrict__ attn_in_w, const float* __restrict__ attn_in_b,
    f16* __restrict__ aob)
{
  __shared__ __align__(16) f16 hs[T_][264];
  __shared__ float qs[256];
  __shared__ float qks[4][256];
  __shared__ float ps[4][T_];
  __shared__ float hb[4][256];
  int b = blockIdx.x, tid = threadIdx.x;
  for (int i = tid; i < T_ * 32; i += 256) {
    int row = i >> 5, cc = (i & 31) * 8;
    *(f16x8*)&hs[row][cc] = *(const f16x8*)&hseq[((size_t)b * T_ + row) * 256 + cc];
  }
  __syncthreads();
  // ---- q phase (was gemm64): q[j] = b_q[j] + h[T-1] . Wq_row_j ----
  {
    int j = tid;
    float acc = attn_in_b[j];
    const f16x8* wr = (const f16x8*)(attninf + (size_t)j * 256);
    for (int cc = 0; cc < 32; cc++) {
      f16x8 wv = wr[cc];
      f16x8 hv = *(const f16x8*)&hs[T_ - 1][cc * 8];
#pragma unroll
      for (int u = 0; u < 8; u++) acc += (float)hv[u] * (float)wv[u];
    }
    qs[j] = acc;
  }
  __syncthreads();
  // ---- qk phase ----
  {
    int j = tid;
#pragma unroll
    for (int h = 0; h < 4; h++) {
      float acc = 0.f;
      for (int d = 0; d < 64; d++)
        acc += qs[h * 64 + d] * attn_in_w[(size_t)(256 + h * 64 + d) * 256 + j];
      qks[h][j] = acc * 0.125f;
    }
  }
  __syncthreads();
  // ---- scores phase ----
  if (tid < T_) {
    float s[4] = {0.f, 0.f, 0.f, 0.f};
    for (int cc = 0; cc < 32; cc++) {
      f16x8 v = *(const f16x8*)&hs[tid][cc * 8];
#pragma unroll
      for (int h = 0; h < 4; h++) {
        float a = 0.f;
#pragma unroll
        for (int j = 0; j < 8; j++) a += qks[h][cc * 8 + j] * (float)v[j];
        s[h] += a;
      }
    }
#pragma unroll
    for (int h = 0; h < 4; h++) ps[h][tid] = s[h];
  }
  __syncthreads();
  // ---- softmax over t (wave w handles head w) ----
  {
    int w = tid >> 6, l = tid & 63;
    float a = ps[w][l], bb = ps[w][l + 64];
    float m = fmaxf(a, bb);
#pragma unroll
    for (int o = 32; o > 0; o >>= 1) m = fmaxf(m, __shfl_xor(m, o, 64));
    float e0 = __expf(a - m), e1 = __expf(bb - m);
    float se = e0 + e1;
#pragma unroll
    for (int o = 32; o > 0; o >>= 1) se += __shfl_xor(se, o, 64);
    float inv = 1.f / se;
    ps[w][l] = e0 * inv; ps[w][l + 64] = e1 * inv;
  }
  __syncthreads();
  // ---- pool ----
  {
    int j = tid;
    float acc[4] = {0.f, 0.f, 0.f, 0.f};
    for (int t = 0; t < T_; t++) {
      float hv = (float)hs[t][j];
#pragma unroll
      for (int h = 0; h < 4; h++) acc[h] += ps[h][t] * hv;
    }
#pragma unroll
    for (int h = 0; h < 4; h++) hb[h][j] = acc[h];
  }
  __syncthreads();
  // ---- vproj phase ----
  {
    int d = tid, h = d >> 6;
    const float4* wr = (const float4*)(attn_in_w + (size_t)(512 + d) * 256);
    float acc = 0.f;
    for (int cc = 0; cc < 64; cc++) {
      float4 w4 = wr[cc];
      acc += w4.x * hb[h][cc * 4] + w4.y * hb[h][cc * 4 + 1]
           + w4.z * hb[h][cc * 4 + 2] + w4.w * hb[h][cc * 4 + 3];
    }
    aob[(size_t)b * 256 + d] = (f16)(acc + attn_in_b[512 + d]);
  }
}

// ---------------- fused tail: gnn-GEMM + gelu/LN + gate-GEMM + final ------
// Per batch-row block. Transposed f16 weights (gnnwT, gatewT) give coalesced
// 512-B column reads. f32 operands throughout (>= old f16-hidcat precision).
__global__ __launch_bounds__(256) void tail_fused_kernel(
    const f16* __restrict__ aggf, const f16* __restrict__ gnnwT,
    const float* __restrict__ gnn_b, const float* __restrict__ lg,
    const float* __restrict__ lb, const float* __restrict__ hid32,
    const f16* __restrict__ gatewT, const float* __restrict__ gate_b,
    const float* __restrict__ outw, const float* __restrict__ outb,
    float* __restrict__ out)
{
  __shared__ float ag[256], yl[256], hl[256];
  int b = blockIdx.x, j = threadIdx.x;
  ag[j] = (float)aggf[(size_t)b * 256 + j];
  hl[j] = hid32[(size_t)b * 256 + j];
  __syncthreads();
  // gnn: pre[j] = gnn_b[j] + agg . gnn_w[j,:]  (gnnwT[k][j] coalesced)
  float acc = gnn_b[j];
#pragma unroll 8
  for (int k = 0; k < 256; k++) acc += ag[k] * (float)gnnwT[k * 256 + j];
  float ge = 0.5f * acc * (1.f + erff(acc * 0.70710678118654752f));
  float mu = blk_sum(ge) * (1.f / 256.f);
  float d = ge - mu;
  float var = blk_sum(d * d) * (1.f / 256.f);
  float y = d * rsqrtf(var + 1e-5f) * lg[j] + lb[j];
  yl[j] = y;
  __syncthreads();
  // gate: g[j] = gate_b[j] + [hidden|enriched] . gate_w[j,:]
  float g = gate_b[j];
#pragma unroll 8
  for (int k = 0; k < 256; k++) g += hl[k] * (float)gatewT[k * 256 + j];
#pragma unroll 8
  for (int k = 0; k < 256; k++) g += yl[k] * (float)gatewT[(256 + k) * 256 + j];
  float gt = sigf(g);
  float comb = gt * y + (1.f - gt) * hl[j];
  float v = comb * outw[j];
  float s = blk_sum(v);
  if (j == 0) out[b] = s + outb[0];
}

// ---------------- one-shot prep: weights + flags + adjn + VSN --------------
// Blocks 0..3352: weight packing (wpk, attninf, attnoutf, gnnwT, gatewT,
//                 biases, flag zeroing).
// Blocks 3353..4376: deg_adjn (bp = blockIdx - 3353), reads adj/sku only.
// Blocks 4377..5400: VSN (b = blockIdx - 4377) -- fully independent of the
//                 weight-prep outputs, so it overlaps instead of serializing.
__global__ void prep_kernel(
    const float* Wih0, const float* Whh0, const float* Wih1, const float* Whh1,
    const float* bih0, const float* bhh0, const float* bih1, const float* bhh1,
    const float* attn_in_w, const float* attn_out_w, const float* gnn_w,
    const float* gate_w, const float* adj, const int* sku,
    const float* x, const float* selw, const float* selb,
    const float* embw, const float* embb,
    f16* wpk0, f16* wpk1, f16* attninf, f16* attnoutf, f16* gnnwT, f16* gatewT,
    float* bias0, float* bias1, int* flagz, f16* adjn, f16* hA)
{
  if (blockIdx.x >= 4377) {
    // ---- VSN: weights softmax + embedding dot, per batch-row ----
    __shared__ float wbs[128][18];
    int b = blockIdx.x - 4377, tid = threadIdx.x;
    if (tid < 128) {
      size_t pos = (size_t)b * 128 + tid;
      const float* xr = x + pos * F_;
      float xv[F_];
#pragma unroll
      for (int f = 0; f < F_; f++) xv[f] = xr[f];
      float wv[F_]; float mx = -1e30f;
#pragma unroll
      for (int f = 0; f < F_; f++) {
        float s = selb[f];
#pragma unroll
        for (int f2 = 0; f2 < F_; f2++) s += xv[f2] * selw[f * F_ + f2];
        wv[f] = s; mx = fmaxf(mx, s);
      }
      float se = 0.f;
#pragma unroll
      for (int f = 0; f < F_; f++) { wv[f] = __expf(wv[f] - mx); se += wv[f]; }
      float inv = 1.f / se;
#pragma unroll
      for (int f = 0; f < F_; f++) {
        float wt = wv[f] * inv;
        wbs[tid][f] = wt; wbs[tid][9 + f] = wt * xv[f];
      }
    }
    __syncthreads();
    int j = threadIdx.x;
    float ew[F_], eb[F_];
#pragma unroll
    for (int f = 0; f < F_; f++) { ew[f] = embw[f * H_ + j]; eb[f] = embb[f * H_ + j]; }
    for (int i = 0; i < 128; i++) {
      float h = 0.f;
#pragma unroll
      for (int f = 0; f < F_; f++) h += wbs[i][9 + f] * ew[f] + wbs[i][f] * eb[f];
      hA[((size_t)b * 128 + i) * H_ + j] = (f16)h;
    }
    return;
  }
  if (blockIdx.x >= 3353) {
    int bp = blockIdx.x - 3353;
    int p = sku[bp];
    int tid = threadIdx.x;
    float s = 0.f;
    for (int j = tid; j < P_; j += 256) s += adj[(size_t)p * P_ + j];
    float tot = blk_sum(s);
    float inv = 1.f / fmaxf(tot, 1e-6f);
    for (int b = tid; b < B_; b += 256)
      adjn[(size_t)bp * B_ + b] = (f16)(adj[(size_t)p * P_ + sku[b]] * inv);
    return;
  }
  int idx = blockIdx.x * 256 + threadIdx.x;
  if (idx < 524288) {
    int j = idx & 7, lane = (idx >> 3) & 63, k = (idx >> 9) & 15;
    int g = (idx >> 13) & 3, w = (idx >> 15) & 3, s = (idx >> 17) & 3;
    int row = g * 256 + s * 64 + w * 16 + (lane & 15);
    int col = k * 32 + (lane >> 4) * 8 + j;
    float v0 = col < 256 ? Wih0[(size_t)row * 256 + col] : Whh0[(size_t)row * 256 + col - 256];
    float v1 = col < 256 ? Wih1[(size_t)row * 256 + col] : Whh1[(size_t)row * 256 + col - 256];
    wpk0[idx] = (f16)v0;
    wpk1[idx] = (f16)v1;
    return;
  }
  int i = idx - 524288;
  if (i < 65536) { attninf[i] = (f16)attn_in_w[i]; return; }
  i -= 65536;
  if (i < 65536) { attnoutf[i] = (f16)attn_out_w[i]; return; }
  i -= 65536;
  if (i < 65536) {   // transposed gnn weights: gnnwT[k][j] = gnn_w[j][k]
    int j = i & 255, k = i >> 8;
    gnnwT[i] = (f16)gnn_w[(size_t)j * 256 + k];
    return;
  }
  i -= 65536;
  if (i < 131072) {  // transposed gate weights: gatewT[k][j] = gate_w[j][k]
    int j = i & 255, k = i >> 8;
    gatewT[i] = (f16)gate_w[(size_t)j * 512 + k];
    return;
  }
  i -= 131072;
  if (i < 1024) { bias0[i] = bih0[i] + bhh0[i]; return; }
  i -= 1024;
  if (i < 1024) { bias1[i] = bih1[i] + bhh1[i]; return; }
  i -= 1024;
  if (i < 4096) { flagz[i] = 0; return; }
}

// ---------------- launch ----------------
extern "C" void kernel_launch(void* const* d_in, const int* in_sizes, int n_in,
                              void* d_out, int out_size, void* d_ws, size_t ws_size,
                              hipStream_t stream)
{
  const float* x         = (const float*)d_in[0];
  const int*   sku       = (const int*)  d_in[1];
  const float* adj       = (const float*)d_in[2];
  const float* vsn_emb_w = (const float*)d_in[3];
  const float* vsn_emb_b = (const float*)d_in[4];
  const float* vsn_sel_w = (const float*)d_in[5];
  const float* vsn_sel_b = (const float*)d_in[6];
  const float* Wih0 = (const float*)d_in[7];
  const float* Whh0 = (const float*)d_in[8];
  const float* bih0 = (const float*)d_in[9];
  const float* bhh0 = (const float*)d_in[10];
  const float* Wih1 = (const float*)d_in[11];
  const float* Whh1 = (const float*)d_in[12];
  const float* bih1 = (const float*)d_in[13];
  const float* bhh1 = (const float*)d_in[14];
  const float* attn_in_w  = (const float*)d_in[15];
  const float* attn_in_b  = (const float*)d_in[16];
  const float* attn_out_w = (const float*)d_in[17];
  const float* attn_out_b = (const float*)d_in[18];
  const float* gnn_w  = (const float*)d_in[19];
  const float* gnn_b  = (const float*)d_in[20];
  const float* ln_g   = (const float*)d_in[21];
  const float* ln_b   = (const float*)d_in[22];
  const float* gate_w = (const float*)d_in[23];
  const float* gate_b = (const float*)d_in[24];
  const float* out_w  = (const float*)d_in[25];
  const float* out_b  = (const float*)d_in[26];
  (void)in_sizes; (void)n_in; (void)out_size; (void)ws_size;

  char* wsb = (char*)d_ws;
  size_t off = 0;
  auto alloc = [&](size_t bytes) -> void* {
    void* p = wsb + off;
    off += (bytes + 255) & ~(size_t)255;
    return p;
  };
  f16* hA      = (f16*)alloc((size_t)B_ * T_ * H_ * 2);   // 67 MB, in-place pipeline
  f16* wpk0    = (f16*)alloc((size_t)1024 * 512 * 2);
  f16* wpk1    = (f16*)alloc((size_t)1024 * 512 * 2);
  f16* attninf = (f16*)alloc((size_t)256 * 256 * 2);
  f16* attnoutf= (f16*)alloc((size_t)256 * 256 * 2);
  f16* gnnwT   = (f16*)alloc((size_t)256 * 256 * 2);
  f16* gatewT  = (f16*)alloc((size_t)512 * 256 * 2);
  float* bias0 = (float*)alloc(1024 * 4);
  float* bias1 = (float*)alloc(1024 * 4);
  int* cnt0    = (int*)alloc(32 * 64 * 4);   // per-group flag lines (256B)
  int* cnt1    = (int*)alloc(32 * 64 * 4);   // (cnt0,cnt1 contiguous: 4096 ints)
  f16* adjn    = (f16*)alloc((size_t)B_ * B_ * 2);
  f16* aob     = (f16*)alloc((size_t)B_ * 256 * 2);
  float* hidden32 = (float*)alloc((size_t)B_ * 256 * 4);
  f16* hT      = (f16*)alloc((size_t)256 * B_ * 2);
  f16* aggf    = (f16*)alloc((size_t)B_ * 256 * 2);

  // 0+1) prep: weight packing + flags + adjn + VSN (one launch)
  prep_kernel<<<5401, 256, 0, stream>>>(
      Wih0, Whh0, Wih1, Whh1, bih0, bhh0, bih1, bhh1,
      attn_in_w, attn_out_w, gnn_w, gate_w, adj, sku,
      x, vsn_sel_w, vsn_sel_b, vsn_emb_w, vsn_emb_b,
      wpk0, wpk1, attninf, attnoutf, gnnwT, gatewT, bias0, bias1, cnt0, adjn, hA);

  // 2) both LSTM layers pipelined in ONE kernel, in place on hA
  lstm_pipe<<<256, 256, 0, stream>>>(hA, wpk0, wpk1, bias0, bias1, cnt0, cnt1);

  // 3) attention (q + qk + pool + vproj fused)
  attn_fused_kernel<<<B_, 256, 0, stream>>>(hA, attninf, attn_in_w, attn_in_b, aob);
  // 4) hidden = aob @ attn_out^T (f32 out + transposed f16 hT in epilogue)
  dim3 g64(B_ / 64, 256 / 64);
  gemm64<<<g64, 256, 0, stream>>>(aob, 256, attnoutf, 256, attn_out_b,
                                  nullptr, 0, hidden32, 256, hT, B_,
                                  B_, 256, 256);
  // 5) aggregated = adjn @ hT^T
  gemm64<<<g64, 256, 0, stream>>>(adjn, 1024, hT, 1024, nullptr,
                                  aggf, 256, nullptr, 0, nullptr, 0,
                                  B_, 256, 1024);
  // 6) gnn + gelu/LN + gate + combine + out (one per-row kernel)
  tail_fused_kernel<<<B_, 256, 0, stream>>>(aggf, gnnwT, gnn_b, ln_g, ln_b,
                                            hidden32, gatewT, gate_b,
                                            out_w, out_b, (float*)d_out);
}